// Round 19
// baseline (306.570 us; speedup 1.0000x reference)
//
#include <hip/hip_runtime.h>
#include <hip/hip_bf16.h>

#define EPS 1e-5f

typedef __hip_bfloat16 bf16;
typedef __attribute__((ext_vector_type(8))) short short8v;   // 8 bf16 = 4 VGPRs
typedef __attribute__((ext_vector_type(4))) short short4v;   // 4 bf16 = 2 VGPRs
typedef __attribute__((ext_vector_type(4))) float f32x4;

// K=16 bf16 MFMA (A,B = 4 bf16/lane). Fallback: zero-padded K=32.
__device__ inline f32x4 mfma16bf(short4v a, short4v b, f32x4 c) {
#if __has_builtin(__builtin_amdgcn_mfma_f32_16x16x16bf16_1k)
  return __builtin_amdgcn_mfma_f32_16x16x16bf16_1k(a, b, c, 0, 0, 0);
#else
  short8v a8 = {a[0], a[1], a[2], a[3], 0, 0, 0, 0};
  short8v b8 = {b[0], b[1], b[2], b[3], 0, 0, 0, 0};
  return __builtin_amdgcn_mfma_f32_16x16x32_bf16(a8, b8, c, 0, 0, 0);
#endif
}

__device__ inline void load_lds16(const void* g, void* l) {
  __builtin_amdgcn_global_load_lds(
      (const __attribute__((address_space(1))) void*)g,
      (__attribute__((address_space(3))) void*)l, 16, 0, 0);
}

__device__ inline unsigned pack_bf16x2(float a, float b) {
  union { bf16 h[2]; unsigned u; } cv;
  cv.h[0] = __float2bfloat16(a);
  cv.h[1] = __float2bfloat16(b);
  return cv.u;
}

__device__ inline float4 bf4_to_f4(ushort4 u) {
  union { ushort4 u4; bf16 h[4]; } c;
  c.u4 = u;
  return make_float4(__bfloat162float(c.h[0]), __bfloat162float(c.h[1]),
                     __bfloat162float(c.h[2]), __bfloat162float(c.h[3]));
}

#define L2E 1.4426950408889634f
#define QSCALE_L2E 0.25504333961883236f  // 32^-0.5 * log2(e), folded into q

// ---------------------------------------------------------------------------
// Fused weight conversion. gvec[s] != null: fold LN gain g[d] into W[n][d]
// (LN-fusion for phase B/C GEMMs); K is always 256 for folded segments.
// ---------------------------------------------------------------------------
struct CvtArgs {
  const float* src[8];
  bf16* dst[8];
  const float* gvec[8];
  int n4[8];
  int scale_n4[8];
};

__global__ __launch_bounds__(256) void cvt_all_kernel(CvtArgs a) {
  int i = blockIdx.x * 256 + threadIdx.x;
#pragma unroll
  for (int s = 0; s < 8; ++s) {
    if (i < a.n4[s]) {
      float4 v = reinterpret_cast<const float4*>(a.src[s])[i];
      float sc = (i < a.scale_n4[s]) ? QSCALE_L2E : 1.0f;
      float4 gv = make_float4(1.f, 1.f, 1.f, 1.f);
      if (a.gvec[s])
        gv = *reinterpret_cast<const float4*>(a.gvec[s] + (i & 63) * 4);
      union { ushort4 u; bf16 h[4]; } cv;
      cv.h[0] = __float2bfloat16(v.x * sc * gv.x);
      cv.h[1] = __float2bfloat16(v.y * sc * gv.y);
      cv.h[2] = __float2bfloat16(v.z * sc * gv.z);
      cv.h[3] = __float2bfloat16(v.w * sc * gv.w);
      reinterpret_cast<ushort4*>(a.dst[s])[i] = cv.u;
      return;
    }
    i -= a.n4[s];
  }
}

__global__ __launch_bounds__(256) void bias_concat_kernel(
    const float* rq, const float* rg, float* br) {
  int i = blockIdx.x * 256 + threadIdx.x;  // 0..1023
  float v = (i < 768) ? rq[i] : rg[i - 768];
  br[i] = (i < 256) ? v * QSCALE_L2E : v;
}

// ---------------------------------------------------------------------------
// LN-fusion prep: per output col n, C1[n] = s_n * sum_d W[n][d]*g[d],
// beta[n] = s_n * (bias[n] + sum_d W[n][d]*lnb[d]).
// wid 0..1023 = col qkvg (g=ln_mc), 1024..2047 = t_w1 (g=ln_t).
// ---------------------------------------------------------------------------
__global__ __launch_bounds__(256) void lnfuse_prep_kernel(
    const float* cqkv_w, const float* cgate_w, const float* cqkv_b,
    const float* cgate_b, const float* mc_g, const float* mc_b,
    const float* t1_w, const float* t1_b, const float* t_g, const float* t_b_,
    float* c1c, float* betac, float* c1t, float* betat) {
  int wid = blockIdx.x * 4 + (threadIdx.x >> 6);
  int lane = threadIdx.x & 63;
  bool isT = wid >= 1024;
  int n = isT ? wid - 1024 : wid;
  const float* Wrow;
  float bias0;
  const float *g, *bb;
  if (isT) {
    Wrow = t1_w + (size_t)n * 256; bias0 = t1_b[n]; g = t_g; bb = t_b_;
  } else if (n < 768) {
    Wrow = cqkv_w + (size_t)n * 256; bias0 = cqkv_b[n]; g = mc_g; bb = mc_b;
  } else {
    Wrow = cgate_w + (size_t)(n - 768) * 256; bias0 = cgate_b[n - 768];
    g = mc_g; bb = mc_b;
  }
  float4 wv = *reinterpret_cast<const float4*>(Wrow + lane * 4);
  float4 gv = *reinterpret_cast<const float4*>(g + lane * 4);
  float4 bv = *reinterpret_cast<const float4*>(bb + lane * 4);
  float s1 = wv.x * gv.x + wv.y * gv.y + wv.z * gv.z + wv.w * gv.w;
  float s2 = wv.x * bv.x + wv.y * bv.y + wv.z * bv.z + wv.w * bv.w;
#pragma unroll
  for (int off = 32; off >= 1; off >>= 1) {
    s1 += __shfl_xor(s1, off);
    s2 += __shfl_xor(s2, off);
  }
  if (lane == 0) {
    float s = (!isT && n < 256) ? QSCALE_L2E : 1.0f;
    if (isT) {
      c1t[n] = s1;
      betat[n] = bias0 + s2;
    } else {
      c1c[n] = s * s1;
      betac[n] = s * (bias0 + s2);
    }
  }
}

// ---------------------------------------------------------------------------
// LN stats over bf16 rows: st[row] = {mu*inv, inv}. Wave handles 2 rows.
// ---------------------------------------------------------------------------
__global__ __launch_bounds__(512) void ln_stats_kernel(
    const bf16* __restrict__ in, float2* __restrict__ st) {
  int tid = threadIdx.x;
  int w = tid >> 6, lane = tid & 63;
  int row0 = blockIdx.x * 16 + w * 2;
  float4 x0 = bf4_to_f4(
      reinterpret_cast<const ushort4*>(in + (size_t)row0 * 256)[lane]);
  float4 x1 = bf4_to_f4(
      reinterpret_cast<const ushort4*>(in + (size_t)(row0 + 1) * 256)[lane]);
  float s0 = x0.x + x0.y + x0.z + x0.w;
  float q0 = x0.x * x0.x + x0.y * x0.y + x0.z * x0.z + x0.w * x0.w;
  float s1 = x1.x + x1.y + x1.z + x1.w;
  float q1 = x1.x * x1.x + x1.y * x1.y + x1.z * x1.z + x1.w * x1.w;
#pragma unroll
  for (int off = 32; off >= 1; off >>= 1) {
    s0 += __shfl_xor(s0, off);
    q0 += __shfl_xor(q0, off);
    s1 += __shfl_xor(s1, off);
    q1 += __shfl_xor(q1, off);
  }
  if (lane == 0) {
    float m0 = s0 * (1.0f / 256.0f);
    float i0 = rsqrtf(q0 * (1.0f / 256.0f) - m0 * m0 + EPS);
    st[row0] = make_float2(m0 * i0, i0);
  }
  if (lane == 32) {
    float m1 = s1 * (1.0f / 256.0f);
    float i1 = rsqrtf(q1 * (1.0f / 256.0f) - m1 * m1 + EPS);
    st[row0 + 1] = make_float2(m1 * i1, i1);
  }
}

// ---------------------------------------------------------------------------
// Batched LayerNorm (256 cols) fp32 -> bf16 (phase A only).
// ---------------------------------------------------------------------------
__global__ __launch_bounds__(512) void ln256_bf_kernel(
    const float* __restrict__ in, bf16* __restrict__ out,
    const float* __restrict__ g, const float* __restrict__ b) {
  int tid = threadIdx.x;
  int w = tid >> 6, lane = tid & 63;
  int row0 = blockIdx.x * 16 + w * 2;
  float4 x0 = reinterpret_cast<const float4*>(in + (size_t)row0 * 256)[lane];
  float4 x1 =
      reinterpret_cast<const float4*>(in + (size_t)(row0 + 1) * 256)[lane];
  float4 gv = reinterpret_cast<const float4*>(g)[lane];
  float4 bv = reinterpret_cast<const float4*>(b)[lane];

  float s0 = x0.x + x0.y + x0.z + x0.w;
  float q0 = x0.x * x0.x + x0.y * x0.y + x0.z * x0.z + x0.w * x0.w;
  float s1 = x1.x + x1.y + x1.z + x1.w;
  float q1 = x1.x * x1.x + x1.y * x1.y + x1.z * x1.z + x1.w * x1.w;
#pragma unroll
  for (int off = 32; off >= 1; off >>= 1) {
    s0 += __shfl_xor(s0, off);
    q0 += __shfl_xor(q0, off);
    s1 += __shfl_xor(s1, off);
    q1 += __shfl_xor(q1, off);
  }
  float m0 = s0 * (1.0f / 256.0f);
  float i0 = rsqrtf(q0 * (1.0f / 256.0f) - m0 * m0 + EPS);
  float m1 = s1 * (1.0f / 256.0f);
  float i1 = rsqrtf(q1 * (1.0f / 256.0f) - m1 * m1 + EPS);

  union { ushort4 u; bf16 h[4]; } c0, c1;
  c0.h[0] = __float2bfloat16((x0.x - m0) * i0 * gv.x + bv.x);
  c0.h[1] = __float2bfloat16((x0.y - m0) * i0 * gv.y + bv.y);
  c0.h[2] = __float2bfloat16((x0.z - m0) * i0 * gv.z + bv.z);
  c0.h[3] = __float2bfloat16((x0.w - m0) * i0 * gv.w + bv.w);
  c1.h[0] = __float2bfloat16((x1.x - m1) * i1 * gv.x + bv.x);
  c1.h[1] = __float2bfloat16((x1.y - m1) * i1 * gv.y + bv.y);
  c1.h[2] = __float2bfloat16((x1.z - m1) * i1 * gv.z + bv.z);
  c1.h[3] = __float2bfloat16((x1.w - m1) * i1 * gv.w + bv.w);
  reinterpret_cast<ushort4*>(out + (size_t)row0 * 256)[lane] = c0.u;
  reinterpret_cast<ushort4*>(out + (size_t)(row0 + 1) * 256)[lane] = c1.u;
}

// ---------------------------------------------------------------------------
// Pair bias via MFMA: bT[h][row] = L2E * dot(LN(pair[row,:]), bw[h,:])
// ---------------------------------------------------------------------------
__global__ __launch_bounds__(256) void pair_bias_kernel(
    const float* __restrict__ pair, const float* __restrict__ g,
    const float* __restrict__ b, const float* __restrict__ bw,
    float* __restrict__ bT) {
  int tid = threadIdx.x;
  int w = tid >> 6, lane = tid & 63;
  int l15 = lane & 15, l4 = lane >> 4;
  int rowbase = blockIdx.x * 64 + w * 16;
  const float* zrow = pair + (size_t)(rowbase + l15) * 128;

  float z[4][8];
#pragma unroll
  for (int kk = 0; kk < 4; ++kk) {
    float4 a0 = *reinterpret_cast<const float4*>(zrow + kk * 32 + l4 * 8);
    float4 a1 = *reinterpret_cast<const float4*>(zrow + kk * 32 + l4 * 8 + 4);
    z[kk][0] = a0.x; z[kk][1] = a0.y; z[kk][2] = a0.z; z[kk][3] = a0.w;
    z[kk][4] = a1.x; z[kk][5] = a1.y; z[kk][6] = a1.z; z[kk][7] = a1.w;
  }
  float s = 0.0f, sq = 0.0f;
#pragma unroll
  for (int kk = 0; kk < 4; ++kk)
#pragma unroll
    for (int e = 0; e < 8; ++e) {
      s += z[kk][e];
      sq += z[kk][e] * z[kk][e];
    }
  s += __shfl_xor(s, 16);
  s += __shfl_xor(s, 32);
  sq += __shfl_xor(sq, 16);
  sq += __shfl_xor(sq, 32);
  float mu = s * (1.0f / 128.0f);
  float inv = rsqrtf(sq * (1.0f / 128.0f) - mu * mu + EPS);

  f32x4 acc = {0.f, 0.f, 0.f, 0.f};
#pragma unroll
  for (int kk = 0; kk < 4; ++kk) {
    const float* gp = g + kk * 32 + l4 * 8;
    const float* bp = b + kk * 32 + l4 * 8;
    float4 g0 = *reinterpret_cast<const float4*>(gp);
    float4 g1 = *reinterpret_cast<const float4*>(gp + 4);
    float4 b0 = *reinterpret_cast<const float4*>(bp);
    float4 b1 = *reinterpret_cast<const float4*>(bp + 4);
    float gv[8] = {g0.x, g0.y, g0.z, g0.w, g1.x, g1.y, g1.z, g1.w};
    float bv[8] = {b0.x, b0.y, b0.z, b0.w, b1.x, b1.y, b1.z, b1.w};
    union { short8v v; bf16 h[8]; } af;
#pragma unroll
    for (int e = 0; e < 8; ++e)
      af.h[e] = __float2bfloat16((z[kk][e] - mu) * inv * gv[e] + bv[e]);
    union { short8v v; bf16 h[8]; } bwf;
    if (l15 < 8) {
      const float* wp = bw + l15 * 128 + kk * 32 + l4 * 8;
      float4 w0 = *reinterpret_cast<const float4*>(wp);
      float4 w1 = *reinterpret_cast<const float4*>(wp + 4);
      float wv[8] = {w0.x, w0.y, w0.z, w0.w, w1.x, w1.y, w1.z, w1.w};
#pragma unroll
      for (int e = 0; e < 8; ++e) bwf.h[e] = __float2bfloat16(wv[e]);
    } else {
      bwf.v = short8v{0, 0, 0, 0, 0, 0, 0, 0};
    }
    acc = __builtin_amdgcn_mfma_f32_16x16x32_bf16(af.v, bwf.v, acc, 0, 0, 0);
  }
  if (l15 < 8) {
    float4 o4 =
        make_float4(acc[0] * L2E, acc[1] * L2E, acc[2] * L2E, acc[3] * L2E);
    *reinterpret_cast<float4*>(&bT[(size_t)l15 * 65536 + rowbase + l4 * 4]) =
        o4;
  }
}

// ---------------------------------------------------------------------------
// MFMA GEMM, double-buffered, XCD-swizzled, swapped operands (col-contiguous
// stores), 128x128 tile.
// AMAP=1: A row r read from r*256+bm. OMAP=1: out/aux row lr -> lr*256+bm.
// LNF=1: A is RAW bf16 residual; weights are g-folded; epilogue applies
//        v = inv*acc - (mu*inv)*c1[col] + beta[col] (beta passed via bias).
// EPI 0: bf16 out   EPI 2: out = aux + acc + bias   EPI 3: bf16 relu out
// ---------------------------------------------------------------------------
template <int EPI, int AMAP, int OMAP, int AUXB, int OUTB, int LNF>
__global__ __launch_bounds__(256) void gemm_mfma_kernel(
    const bf16* __restrict__ A, const bf16* __restrict__ W,
    const float* __restrict__ bias, const void* __restrict__ aux, void* out,
    int N, int K, int nbn, const float2* __restrict__ stats,
    const float* __restrict__ c1) {
  __shared__ __align__(16) short As[2][128 * 32];
  __shared__ __align__(16) short Bs[2][128 * 32];
  int nwg = gridDim.x;
  int qch = nwg >> 3;
  int flat = blockIdx.x;
  int wg = (flat & 7) * qch + (flat >> 3);
  int bm = wg / nbn, bn = wg % nbn;
  int tid = threadIdx.x;
  int w = tid >> 6, lane = tid & 63;
  int wr = w >> 1, wc = w & 1;
  int c0 = w * 64 + lane;
  int srow = c0 >> 2, skq = c0 & 3;
  const short* Aptr = (const short*)A;
  const short* Wbase = (const short*)(W + (size_t)(bn * 128) * K);
  f32x4 acc[4][4] = {};
  int lrow = lane & 15, kq = lane >> 4;

  auto arow = [&](int r) -> size_t {
    return AMAP ? ((size_t)r * 256 + bm) : ((size_t)(bm * 128 + r));
  };
  auto stage = [&](int buf, int k0) {
    load_lds16(Aptr + arow(srow) * K + k0 + skq * 8, &As[buf][c0 * 8]);
    load_lds16(Aptr + arow(srow + 64) * K + k0 + skq * 8,
               &As[buf][(256 + c0) * 8]);
    load_lds16(Wbase + (size_t)srow * K + k0 + skq * 8, &Bs[buf][c0 * 8]);
    load_lds16(Wbase + (size_t)(srow + 64) * K + k0 + skq * 8,
               &Bs[buf][(256 + c0) * 8]);
  };

  stage(0, 0);
  __syncthreads();
  int nk = K >> 5;
  for (int t = 0; t < nk; ++t) {
    int cur = t & 1;
    if (t + 1 < nk) stage(cur ^ 1, (t + 1) << 5);
    short8v af[4], bfv[4];
#pragma unroll
    for (int i = 0; i < 4; ++i)
      af[i] = *reinterpret_cast<const short8v*>(
          &As[cur][(wr * 64 + i * 16 + lrow) * 32 + kq * 8]);
#pragma unroll
    for (int j = 0; j < 4; ++j)
      bfv[j] = *reinterpret_cast<const short8v*>(
          &Bs[cur][(wc * 64 + j * 16 + lrow) * 32 + kq * 8]);
#pragma unroll
    for (int i = 0; i < 4; ++i)
#pragma unroll
      for (int j = 0; j < 4; ++j)
        acc[i][j] = __builtin_amdgcn_mfma_f32_16x16x32_bf16(bfv[j], af[i],
                                                            acc[i][j], 0, 0, 0);
    __syncthreads();
  }

  float2 stv[4];
  if (LNF) {
#pragma unroll
    for (int i = 0; i < 4; ++i)
      stv[i] = stats[arow(wr * 64 + i * 16 + lrow)];
  }

  float* outF = (float*)out;
  bf16* outB = (bf16*)out;
  const float* auxF = (const float*)aux;
  const bf16* auxB = (const bf16*)aux;
#pragma unroll
  for (int j = 0; j < 4; ++j) {
    int cc = bn * 128 + wc * 64 + j * 16 + kq * 4;
    float4 bv4 = bias ? *reinterpret_cast<const float4*>(bias + cc)
                      : make_float4(0.f, 0.f, 0.f, 0.f);
    float4 c1v = make_float4(0.f, 0.f, 0.f, 0.f);
    if (LNF) c1v = *reinterpret_cast<const float4*>(c1 + cc);
#pragma unroll
    for (int i = 0; i < 4; ++i) {
      int lr = wr * 64 + i * 16 + lrow;
      size_t off = OMAP ? (((size_t)lr * 256 + bm) * N + cc)
                        : ((size_t)(bm * 128 + lr) * N + cc);
      float v0, v1, v2, v3;
      if (LNF) {
        float inv = stv[i].y, mi = stv[i].x;
        v0 = inv * acc[i][j][0] - mi * c1v.x + bv4.x;
        v1 = inv * acc[i][j][1] - mi * c1v.y + bv4.y;
        v2 = inv * acc[i][j][2] - mi * c1v.z + bv4.z;
        v3 = inv * acc[i][j][3] - mi * c1v.w + bv4.w;
      } else {
        v0 = acc[i][j][0] + bv4.x;
        v1 = acc[i][j][1] + bv4.y;
        v2 = acc[i][j][2] + bv4.z;
        v3 = acc[i][j][3] + bv4.w;
      }
      if (EPI == 2) {
        float4 av = AUXB
                        ? bf4_to_f4(*reinterpret_cast<const ushort4*>(auxB + off))
                        : *reinterpret_cast<const float4*>(auxF + off);
        v0 += av.x; v1 += av.y; v2 += av.z; v3 += av.w;
      } else if (EPI == 3) {
        v0 = fmaxf(v0, 0.0f); v1 = fmaxf(v1, 0.0f);
        v2 = fmaxf(v2, 0.0f); v3 = fmaxf(v3, 0.0f);
      }
      if (OUTB || EPI == 0 || EPI == 3) {
        union { ushort4 u; bf16 h[4]; } cv;
        cv.h[0] = __float2bfloat16(v0);
        cv.h[1] = __float2bfloat16(v1);
        cv.h[2] = __float2bfloat16(v2);
        cv.h[3] = __float2bfloat16(v3);
        *reinterpret_cast<ushort4*>(outB + off) = cv.u;
      } else {
        *reinterpret_cast<float4*>(outF + off) = make_float4(v0, v1, v2, v3);
      }
    }
  }
}

// ---------------------------------------------------------------------------
// MFMA flash attention + fused gating, P-in-register, 512 threads (8 waves).
// ROWMODE: block = (s,h), 256 q / 256 kv, pair bias.
// !ROWMODE: block = (r-pair, h): two independent 128/128 sub-problems.
// ---------------------------------------------------------------------------
template <bool ROWMODE>
__global__ __launch_bounds__(512) void attn_mfma_kernel(
    const bf16* __restrict__ qkv, const float* __restrict__ bT,
    bf16* __restrict__ o) {
  constexpr int KVLEN = ROWMODE ? 256 : 128;
  constexpr int NSUB = ROWMODE ? 1 : 2;
  constexpr int QT = 2;
  constexpr int KOUT = KVLEN / 64;
  constexpr int KSZ = KVLEN * 32;
  __shared__ __align__(16) short K_lds[NSUB * KSZ];
  __shared__ __align__(16) short Vt_lds[NSUB * 32 * KVLEN];

  int b = blockIdx.x;
  int idx = b >> 3, h = b & 7;
  int tid = threadIdx.x;
  int w = tid >> 6, lane = tid & 63;
  int l15 = lane & 15, l4 = lane >> 4;
  int sub = ROWMODE ? 0 : (w >> 2);
  const short* qb =
      (const short*)qkv + ((size_t)idx * NSUB + sub) * (KVLEN * 1024);
  const bf16* qbh = (const bf16*)qb;
  bf16* ob = o + ((size_t)idx * NSUB + sub) * (KVLEN * 256);

#pragma unroll
  for (int rnd = 0; rnd < 2; ++rnd) {
    int c = rnd * 512 + tid;
    int sc = c / (KVLEN * 4);
    int cc = c - sc * (KVLEN * 4);
    int row = cc >> 2;
    int kq = (cc & 3) ^ ((row >> 1) & 3);
    const short* qs =
        (const short*)qkv + ((size_t)idx * NSUB + sc) * (KVLEN * 1024);
    load_lds16(qs + (size_t)row * 1024 + 256 + h * 32 + kq * 8,
               &K_lds[sc * KSZ + cc * 8]);
  }
  {
    int tt = tid;
    int sv = tt / (KVLEN * 2);
    int t2 = tt - sv * (KVLEN * 2);
    int kp = t2 >> 2;
    int cc = (t2 & 3) * 8;
    const short* qs =
        (const short*)qkv + ((size_t)idx * NSUB + sv) * (KVLEN * 1024);
    short8v va = *reinterpret_cast<const short8v*>(
        qs + (size_t)(2 * kp) * 1024 + 512 + h * 32 + cc);
    short8v vb = *reinterpret_cast<const short8v*>(
        qs + (size_t)(2 * kp + 1) * 1024 + 512 + h * 32 + cc);
    int k = 2 * kp;
    int u = k >> 3;
    int klo = k & 7;
#pragma unroll
    for (int e = 0; e < 8; ++e) {
      int cI = cc + e;
      int up = u ^ (cI & 7);
      unsigned pk = (unsigned)(unsigned short)va[e] |
                    ((unsigned)(unsigned short)vb[e] << 16);
      *reinterpret_cast<unsigned*>(
          &Vt_lds[sv * 32 * KVLEN + cI * KVLEN + up * 8 + klo]) = pk;
    }
  }
  __syncthreads();

  int q0 = (ROWMODE ? w : (w & 3)) * 32;
  short8v qf[QT];
#pragma unroll
  for (int j = 0; j < QT; ++j)
    qf[j] = *reinterpret_cast<const short8v*>(
        qb + (size_t)(q0 + j * 16 + l15) * 1024 + h * 32 + l4 * 8);

  f32x4 acc_o[QT][2] = {};
  f32x4 acc_l[QT] = {};
  const short4v ones = {0x3F80, 0x3F80, 0x3F80, 0x3F80};  // bf16 1.0
  const f32x4 zf = {0.f, 0.f, 0.f, 0.f};

  f32x4 accs[4];
  short4v P[4];
  float4 bb[4];
  const short* Kb = &K_lds[sub * KSZ];
  const short* Vb = &Vt_lds[sub * 32 * KVLEN];

#define LOAD_BIAS(KT, JJ)                                                   \
  if (ROWMODE) {                                                            \
    const float* bq_ = bT + (size_t)h * 65536 +                             \
                       (size_t)(q0 + (JJ) * 16 + l15) * 256 + (KT) * 64 +   \
                       l4 * 4;                                              \
    _Pragma("unroll") for (int i_ = 0; i_ < 4; ++i_) bb[i_] =               \
        *reinterpret_cast<const float4*>(bq_ + i_ * 16);                    \
  }

#define DO_QK(KT, JJ)                                                       \
  {                                                                         \
    _Pragma("unroll") for (int i_ = 0; i_ < 4; ++i_) {                      \
      int krow_ = (KT) * 64 + i_ * 16 + l15;                                \
      short8v kf_ = *reinterpret_cast<const short8v*>(                      \
          &Kb[krow_ * 32 + ((l4 ^ ((krow_ >> 1) & 3)) * 8)]);               \
      f32x4 cin_ = zf;                                                      \
      if (ROWMODE) {                                                        \
        cin_[0] = bb[i_].x; cin_[1] = bb[i_].y;                             \
        cin_[2] = bb[i_].z; cin_[3] = bb[i_].w;                             \
      }                                                                     \
      accs[i_] = __builtin_amdgcn_mfma_f32_16x16x32_bf16(kf_, qf[JJ], cin_, \
                                                         0, 0, 0);          \
    }                                                                       \
  }

#define DO_EXPPACK()                                                        \
  {                                                                         \
    _Pragma("unroll") for (int i_ = 0; i_ < 4; ++i_) {                      \
      float t0_ = exp2f(accs[i_][0]);                                       \
      float t1_ = exp2f(accs[i_][1]);                                       \
      float t2_ = exp2f(accs[i_][2]);                                       \
      float t3_ = exp2f(accs[i_][3]);                                       \
      union { unsigned u2[2]; short4v s; } pb_;                             \
      pb_.u2[0] = pack_bf16x2(t0_, t1_);                                    \
      pb_.u2[1] = pack_bf16x2(t2_, t3_);                                    \
      P[i_] = pb_.s;                                                        \
    }                                                                       \
  }

#define DO_PV(KT, JJ)                                                       \
  {                                                                         \
    _Pragma("unroll") for (int ks_ = 0; ks_ < 4; ++ks_) {                   \
      _Pragma("unroll") for (int ct_ = 0; ct_ < 2; ++ct_) {                 \
        int cI_ = ct_ * 16 + l15;                                           \
        int u_ = (KT) * 8 + ks_ * 2 + (l4 >> 1);                            \
        short4v vf_ = *reinterpret_cast<const short4v*>(                    \
            &Vb[cI_ * KVLEN + (u_ ^ (cI_ & 7)) * 8 + (l4 & 1) * 4]);        \
        acc_o[JJ][ct_] = mfma16bf(vf_, P[ks_], acc_o[JJ][ct_]);             \
      }                                                                     \
      acc_l[JJ] = mfma16bf(ones, P[ks_], acc_l[JJ]);                        \
    }                                                                       \
  }

  LOAD_BIAS(0, 0);
  DO_QK(0, 0);
  LOAD_BIAS(0, 1);
  DO_EXPPACK();  // pending = (0,0)
#pragma unroll 1
  for (int kt = 0; kt < KOUT; ++kt) {
    DO_QK(kt, 1);
    if (kt + 1 < KOUT) LOAD_BIAS(kt + 1, 0);
    DO_PV(kt, 0);
    DO_EXPPACK();  // pending = (kt,1)
    if (kt + 1 < KOUT) {
      DO_QK(kt + 1, 0);
      LOAD_BIAS(kt + 1, 1);
      DO_PV(kt, 1);
      DO_EXPPACK();  // pending = (kt+1,0)
    }
  }
  DO_PV(KOUT - 1, 1);
#undef LOAD_BIAS
#undef DO_QK
#undef DO_EXPPACK
#undef DO_PV

#pragma unroll
  for (int j = 0; j < QT; ++j) {
    float inv = 1.0f / acc_l[j][0];
    int row = q0 + j * 16 + l15;
    const bf16* grow = qbh + (size_t)row * 1024 + 768 + h * 32;
    bf16* orow = ob + (size_t)row * 256 + h * 32;
#pragma unroll
    for (int ct = 0; ct < 2; ++ct) {
      int cc = ct * 16 + l4 * 4;
      ushort4 gv = *reinterpret_cast<const ushort4*>(grow + cc);
      union { ushort4 u; bf16 h4[4]; } gu, ou;
      gu.u = gv;
#pragma unroll
      for (int r = 0; r < 4; ++r) {
        float gt = __bfloat162float(gu.h4[r]);
        float sg = 1.0f / (1.0f + __expf(-gt));
        ou.h4[r] = __float2bfloat16(acc_o[j][ct][r] * inv * sg);
      }
      *reinterpret_cast<ushort4*>(orow + cc) = ou.u;
    }
  }
}

// ---------------------------------------------------------------------------
extern "C" void kernel_launch(void* const* d_in, const int* in_sizes, int n_in,
                              void* d_out, int out_size, void* d_ws,
                              size_t ws_size, hipStream_t stream) {
  (void)in_sizes; (void)n_in; (void)out_size; (void)ws_size;
  const float* node      = (const float*)d_in[0];
  const float* pair      = (const float*)d_in[1];
  const float* ln_mr_g   = (const float*)d_in[2];
  const float* ln_mr_b   = (const float*)d_in[3];
  const float* ln_z_g    = (const float*)d_in[4];
  const float* ln_z_b    = (const float*)d_in[5];
  const float* b_weights = (const float*)d_in[6];
  const float* row_qkv_w = (const float*)d_in[7];
  const float* row_qkv_b = (const float*)d_in[8];
  const float* row_gate_w= (const float*)d_in[9];
  const float* row_gate_b= (const float*)d_in[10];
  const float* row_o_w   = (const float*)d_in[11];
  const float* out_bias  = (const float*)d_in[12];
  const float* ln_mc_g   = (const float*)d_in[13];
  const float* ln_mc_b   = (const float*)d_in[14];
  const float* col_qkv_w = (const float*)d_in[15];
  const float* col_qkv_b = (const float*)d_in[16];
  const float* col_gate_w= (const float*)d_in[17];
  const float* col_gate_b= (const float*)d_in[18];
  const float* col_o_w   = (const float*)d_in[19];
  const float* col_o_b   = (const float*)d_in[20];
  const float* ln_t_g    = (const float*)d_in[21];
  const float* ln_t_b    = (const float*)d_in[22];
  const float* t_w1      = (const float*)d_in[23];
  const float* t_b1      = (const float*)d_in[24];
  const float* t_w2      = (const float*)d_in[25];
  const float* t_b2      = (const float*)d_in[26];
  float* out = (float*)d_out;

  const size_t NR = 32768;
  char* p = (char*)d_ws;
  bf16* nodeB     = (bf16*)p;  p += NR * 256 * 2;   // bf16 residual stream
  char*  qkv_region = p;       p += NR * 1024 * 2;  // qkvg bf16 / h_bf
  float* buf_bias = (float*)p; p += 8 * 256 * 256 * 4;
  bf16* ln_bf     = (bf16*)p;  p += NR * 256 * 2;
  bf16* g_bf      = (bf16*)p;  p += NR * 256 * 2;
  bf16* qkv_bf = (bf16*)qkv_region;   // [32768][1024]: q|k|v|gate
  bf16* h_bf   = (bf16*)qkv_region;   // phase C: [32768][1024]
  bf16* w_rqkvg = (bf16*)p; p += 1024 * 256 * 2;
  bf16* w_ro    = (bf16*)p; p += 256 * 256 * 2;
  bf16* w_cqkvg = (bf16*)p; p += 1024 * 256 * 2;   // g-folded
  bf16* w_co    = (bf16*)p; p += 256 * 256 * 2;
  bf16* w_t1    = (bf16*)p; p += 1024 * 256 * 2;   // g-folded
  bf16* w_t2    = (bf16*)p; p += 256 * 1024 * 2;
  float* b_rqkvg = (float*)p; p += 1024 * 4;
  float* c1c    = (float*)p; p += 1024 * 4;
  float* betac  = (float*)p; p += 1024 * 4;
  float* c1t    = (float*)p; p += 1024 * 4;
  float* betat  = (float*)p; p += 1024 * 4;
  float2* lstats = (float2*)p; p += NR * 8;

  // ---- weight conversions (g-fold for phase B/C); prep C1/beta ----
  CvtArgs ca;
  ca.src[0] = row_qkv_w;  ca.dst[0] = w_rqkvg;             ca.n4[0] = 49152;
  ca.src[1] = row_gate_w; ca.dst[1] = w_rqkvg + 768 * 256; ca.n4[1] = 16384;
  ca.src[2] = row_o_w;    ca.dst[2] = w_ro;                ca.n4[2] = 16384;
  ca.src[3] = col_qkv_w;  ca.dst[3] = w_cqkvg;             ca.n4[3] = 49152;
  ca.src[4] = col_gate_w; ca.dst[4] = w_cqkvg + 768 * 256; ca.n4[4] = 16384;
  ca.src[5] = col_o_w;    ca.dst[5] = w_co;                ca.n4[5] = 16384;
  ca.src[6] = t_w1;       ca.dst[6] = w_t1;                ca.n4[6] = 65536;
  ca.src[7] = t_w2;       ca.dst[7] = w_t2;                ca.n4[7] = 65536;
  for (int s = 0; s < 8; ++s) { ca.scale_n4[s] = 0; ca.gvec[s] = nullptr; }
  ca.scale_n4[0] = 16384;
  ca.scale_n4[3] = 16384;
  ca.gvec[3] = ln_mc_g;
  ca.gvec[4] = ln_mc_g;
  ca.gvec[6] = ln_t_g;
  cvt_all_kernel<<<1152, 256, 0, stream>>>(ca);
  bias_concat_kernel<<<4, 256, 0, stream>>>(row_qkv_b, row_gate_b, b_rqkvg);
  lnfuse_prep_kernel<<<512, 256, 0, stream>>>(
      col_qkv_w, col_gate_w, col_qkv_b, col_gate_b, ln_mc_g, ln_mc_b, t_w1,
      t_b1, ln_t_g, ln_t_b, c1c, betac, c1t, betat);

  // ---- Phase A: MSARowAttentionWithPairBias ----
  ln256_bf_kernel<<<2048, 512, 0, stream>>>(node, ln_bf, ln_mr_g, ln_mr_b);
  pair_bias_kernel<<<1024, 256, 0, stream>>>(pair, ln_z_g, ln_z_b, b_weights,
                                             buf_bias);
  gemm_mfma_kernel<0, 0, 0, 0, 0, 0><<<2048, 256, 0, stream>>>(
      ln_bf, w_rqkvg, b_rqkvg, nullptr, qkv_bf, 1024, 256, 8, nullptr,
      nullptr);
  attn_mfma_kernel<true><<<1024, 512, 0, stream>>>(qkv_bf, buf_bias, g_bf);
  gemm_mfma_kernel<2, 0, 0, 0, 1, 0><<<512, 256, 0, stream>>>(
      g_bf, w_ro, out_bias, node, nodeB, 256, 256, 2, nullptr, nullptr);

  // ---- Phase B: MSAColumnAttention (LN fused into qkvg GEMM) ----
  ln_stats_kernel<<<2048, 512, 0, stream>>>(nodeB, lstats);
  gemm_mfma_kernel<0, 1, 0, 0, 0, 1><<<2048, 256, 0, stream>>>(
      nodeB, w_cqkvg, betac, nullptr, qkv_bf, 1024, 256, 8, lstats, c1c);
  attn_mfma_kernel<false><<<1024, 512, 0, stream>>>(qkv_bf, nullptr, g_bf);
  gemm_mfma_kernel<2, 0, 1, 1, 1, 0><<<512, 256, 0, stream>>>(
      g_bf, w_co, col_o_b, nodeB, nodeB, 256, 256, 2, nullptr, nullptr);

  // ---- Phase C: MSATransition (LN fused into t1 GEMM) ----
  ln_stats_kernel<<<2048, 512, 0, stream>>>(nodeB, lstats);
  gemm_mfma_kernel<3, 0, 0, 0, 0, 1><<<2048, 256, 0, stream>>>(
      nodeB, w_t1, betat, nullptr, h_bf, 1024, 256, 8, lstats, c1t);
  gemm_mfma_kernel<2, 0, 0, 1, 0, 0><<<512, 256, 0, stream>>>(
      h_bf, w_t2, t_b2, nodeB, out, 256, 1024, 2, nullptr, nullptr);
}

// Round 20
// 291.184 us; speedup vs baseline: 1.0528x; 1.0528x over previous
//
#include <hip/hip_runtime.h>
#include <hip/hip_bf16.h>

#define EPS 1e-5f

typedef __hip_bfloat16 bf16;
typedef __attribute__((ext_vector_type(8))) short short8v;   // 8 bf16 = 4 VGPRs
typedef __attribute__((ext_vector_type(4))) short short4v;   // 4 bf16 = 2 VGPRs
typedef __attribute__((ext_vector_type(4))) float f32x4;

// K=16 bf16 MFMA (A,B = 4 bf16/lane). Fallback: zero-padded K=32.
__device__ inline f32x4 mfma16bf(short4v a, short4v b, f32x4 c) {
#if __has_builtin(__builtin_amdgcn_mfma_f32_16x16x16bf16_1k)
  return __builtin_amdgcn_mfma_f32_16x16x16bf16_1k(a, b, c, 0, 0, 0);
#else
  short8v a8 = {a[0], a[1], a[2], a[3], 0, 0, 0, 0};
  short8v b8 = {b[0], b[1], b[2], b[3], 0, 0, 0, 0};
  return __builtin_amdgcn_mfma_f32_16x16x32_bf16(a8, b8, c, 0, 0, 0);
#endif
}

__device__ inline void load_lds16(const void* g, void* l) {
  __builtin_amdgcn_global_load_lds(
      (const __attribute__((address_space(1))) void*)g,
      (__attribute__((address_space(3))) void*)l, 16, 0, 0);
}

__device__ inline unsigned pack_bf16x2(float a, float b) {
  union { bf16 h[2]; unsigned u; } cv;
  cv.h[0] = __float2bfloat16(a);
  cv.h[1] = __float2bfloat16(b);
  return cv.u;
}

__device__ inline float4 bf4_to_f4(ushort4 u) {
  union { ushort4 u4; bf16 h[4]; } c;
  c.u4 = u;
  return make_float4(__bfloat162float(c.h[0]), __bfloat162float(c.h[1]),
                     __bfloat162float(c.h[2]), __bfloat162float(c.h[3]));
}

#define L2E 1.4426950408889634f
#define QSCALE_L2E 0.25504333961883236f  // 32^-0.5 * log2(e), folded into q

// ---------------------------------------------------------------------------
// Fused weight conversion: 8 (src,dst,n4) segments in ONE launch.
// ---------------------------------------------------------------------------
struct CvtArgs {
  const float* src[8];
  bf16* dst[8];
  int n4[8];
  int scale_n4[8];
};

__global__ __launch_bounds__(256) void cvt_all_kernel(CvtArgs a) {
  int i = blockIdx.x * 256 + threadIdx.x;
#pragma unroll
  for (int s = 0; s < 8; ++s) {
    if (i < a.n4[s]) {
      float4 v = reinterpret_cast<const float4*>(a.src[s])[i];
      float sc = (i < a.scale_n4[s]) ? QSCALE_L2E : 1.0f;
      union { ushort4 u; bf16 h[4]; } cv;
      cv.h[0] = __float2bfloat16(v.x * sc);
      cv.h[1] = __float2bfloat16(v.y * sc);
      cv.h[2] = __float2bfloat16(v.z * sc);
      cv.h[3] = __float2bfloat16(v.w * sc);
      reinterpret_cast<ushort4*>(a.dst[s])[i] = cv.u;
      return;
    }
    i -= a.n4[s];
  }
}

__global__ __launch_bounds__(256) void bias_concat_kernel(
    const float* rq, const float* rg, const float* cq, const float* cg,
    float* br, float* bc) {
  int i = blockIdx.x * 256 + threadIdx.x;  // 0..2047
  if (i < 1024) {
    float v = (i < 768) ? rq[i] : rg[i - 768];
    br[i] = (i < 256) ? v * QSCALE_L2E : v;
  } else {
    int j = i - 1024;
    float v = (j < 768) ? cq[j] : cg[j - 768];
    bc[j] = (j < 256) ? v * QSCALE_L2E : v;
  }
}

// ---------------------------------------------------------------------------
// Batched LayerNorm (256 cols) -> bf16. 512 threads; wave handles 2 rows.
// INB=1: input is bf16 (residual stream); INB=0: fp32.
// ---------------------------------------------------------------------------
template <int INB>
__global__ __launch_bounds__(512) void ln256_bf_kernel(
    const void* __restrict__ in, bf16* __restrict__ out,
    const float* __restrict__ g, const float* __restrict__ b) {
  int tid = threadIdx.x;
  int w = tid >> 6, lane = tid & 63;
  int row0 = blockIdx.x * 16 + w * 2;
  float4 x0, x1;
  if (INB) {
    const bf16* inB = (const bf16*)in;
    x0 = bf4_to_f4(
        reinterpret_cast<const ushort4*>(inB + (size_t)row0 * 256)[lane]);
    x1 = bf4_to_f4(
        reinterpret_cast<const ushort4*>(inB + (size_t)(row0 + 1) * 256)[lane]);
  } else {
    const float* inF = (const float*)in;
    x0 = reinterpret_cast<const float4*>(inF + (size_t)row0 * 256)[lane];
    x1 = reinterpret_cast<const float4*>(inF + (size_t)(row0 + 1) * 256)[lane];
  }
  float4 gv = reinterpret_cast<const float4*>(g)[lane];
  float4 bv = reinterpret_cast<const float4*>(b)[lane];

  float s0 = x0.x + x0.y + x0.z + x0.w;
  float q0 = x0.x * x0.x + x0.y * x0.y + x0.z * x0.z + x0.w * x0.w;
  float s1 = x1.x + x1.y + x1.z + x1.w;
  float q1 = x1.x * x1.x + x1.y * x1.y + x1.z * x1.z + x1.w * x1.w;
#pragma unroll
  for (int off = 32; off >= 1; off >>= 1) {
    s0 += __shfl_xor(s0, off);
    q0 += __shfl_xor(q0, off);
    s1 += __shfl_xor(s1, off);
    q1 += __shfl_xor(q1, off);
  }
  float m0 = s0 * (1.0f / 256.0f);
  float i0 = rsqrtf(q0 * (1.0f / 256.0f) - m0 * m0 + EPS);
  float m1 = s1 * (1.0f / 256.0f);
  float i1 = rsqrtf(q1 * (1.0f / 256.0f) - m1 * m1 + EPS);

  union { ushort4 u; bf16 h[4]; } c0, c1;
  c0.h[0] = __float2bfloat16((x0.x - m0) * i0 * gv.x + bv.x);
  c0.h[1] = __float2bfloat16((x0.y - m0) * i0 * gv.y + bv.y);
  c0.h[2] = __float2bfloat16((x0.z - m0) * i0 * gv.z + bv.z);
  c0.h[3] = __float2bfloat16((x0.w - m0) * i0 * gv.w + bv.w);
  c1.h[0] = __float2bfloat16((x1.x - m1) * i1 * gv.x + bv.x);
  c1.h[1] = __float2bfloat16((x1.y - m1) * i1 * gv.y + bv.y);
  c1.h[2] = __float2bfloat16((x1.z - m1) * i1 * gv.z + bv.z);
  c1.h[3] = __float2bfloat16((x1.w - m1) * i1 * gv.w + bv.w);
  reinterpret_cast<ushort4*>(out + (size_t)row0 * 256)[lane] = c0.u;
  reinterpret_cast<ushort4*>(out + (size_t)(row0 + 1) * 256)[lane] = c1.u;
}

// ---------------------------------------------------------------------------
// Pair bias via MFMA: bT[h][row] = L2E * dot(LN(pair[row,:]), bw[h,:])
// ---------------------------------------------------------------------------
__global__ __launch_bounds__(256) void pair_bias_kernel(
    const float* __restrict__ pair, const float* __restrict__ g,
    const float* __restrict__ b, const float* __restrict__ bw,
    float* __restrict__ bT) {
  int tid = threadIdx.x;
  int w = tid >> 6, lane = tid & 63;
  int l15 = lane & 15, l4 = lane >> 4;
  int rowbase = blockIdx.x * 64 + w * 16;
  const float* zrow = pair + (size_t)(rowbase + l15) * 128;

  float z[4][8];
#pragma unroll
  for (int kk = 0; kk < 4; ++kk) {
    float4 a0 = *reinterpret_cast<const float4*>(zrow + kk * 32 + l4 * 8);
    float4 a1 = *reinterpret_cast<const float4*>(zrow + kk * 32 + l4 * 8 + 4);
    z[kk][0] = a0.x; z[kk][1] = a0.y; z[kk][2] = a0.z; z[kk][3] = a0.w;
    z[kk][4] = a1.x; z[kk][5] = a1.y; z[kk][6] = a1.z; z[kk][7] = a1.w;
  }
  float s = 0.0f, sq = 0.0f;
#pragma unroll
  for (int kk = 0; kk < 4; ++kk)
#pragma unroll
    for (int e = 0; e < 8; ++e) {
      s += z[kk][e];
      sq += z[kk][e] * z[kk][e];
    }
  s += __shfl_xor(s, 16);
  s += __shfl_xor(s, 32);
  sq += __shfl_xor(sq, 16);
  sq += __shfl_xor(sq, 32);
  float mu = s * (1.0f / 128.0f);
  float inv = rsqrtf(sq * (1.0f / 128.0f) - mu * mu + EPS);

  f32x4 acc = {0.f, 0.f, 0.f, 0.f};
#pragma unroll
  for (int kk = 0; kk < 4; ++kk) {
    const float* gp = g + kk * 32 + l4 * 8;
    const float* bp = b + kk * 32 + l4 * 8;
    float4 g0 = *reinterpret_cast<const float4*>(gp);
    float4 g1 = *reinterpret_cast<const float4*>(gp + 4);
    float4 b0 = *reinterpret_cast<const float4*>(bp);
    float4 b1 = *reinterpret_cast<const float4*>(bp + 4);
    float gv[8] = {g0.x, g0.y, g0.z, g0.w, g1.x, g1.y, g1.z, g1.w};
    float bv[8] = {b0.x, b0.y, b0.z, b0.w, b1.x, b1.y, b1.z, b1.w};
    union { short8v v; bf16 h[8]; } af;
#pragma unroll
    for (int e = 0; e < 8; ++e)
      af.h[e] = __float2bfloat16((z[kk][e] - mu) * inv * gv[e] + bv[e]);
    union { short8v v; bf16 h[8]; } bwf;
    if (l15 < 8) {
      const float* wp = bw + l15 * 128 + kk * 32 + l4 * 8;
      float4 w0 = *reinterpret_cast<const float4*>(wp);
      float4 w1 = *reinterpret_cast<const float4*>(wp + 4);
      float wv[8] = {w0.x, w0.y, w0.z, w0.w, w1.x, w1.y, w1.z, w1.w};
#pragma unroll
      for (int e = 0; e < 8; ++e) bwf.h[e] = __float2bfloat16(wv[e]);
    } else {
      bwf.v = short8v{0, 0, 0, 0, 0, 0, 0, 0};
    }
    acc = __builtin_amdgcn_mfma_f32_16x16x32_bf16(af.v, bwf.v, acc, 0, 0, 0);
  }
  if (l15 < 8) {
    float4 o4 =
        make_float4(acc[0] * L2E, acc[1] * L2E, acc[2] * L2E, acc[3] * L2E);
    *reinterpret_cast<float4*>(&bT[(size_t)l15 * 65536 + rowbase + l4 * 4]) =
        o4;
  }
}

// ---------------------------------------------------------------------------
// MFMA GEMM, double-buffered, XCD-swizzled, swapped operands (col-contiguous
// stores), 128x128 tile.
// AMAP=1: A row s read from s*256+bm. OMAP=1: out/aux row lr -> lr*256+bm.
// EPI 0: bf16 out = acc + bias
// EPI 2: out = aux + acc + bias; AUXB: aux is bf16; OUTB: out is bf16
// EPI 3: bf16 out = relu(acc+bias)
// ---------------------------------------------------------------------------
template <int EPI, int AMAP, int OMAP, int AUXB, int OUTB>
__global__ __launch_bounds__(256) void gemm_mfma_kernel(
    const bf16* __restrict__ A, const bf16* __restrict__ W,
    const float* __restrict__ bias, const void* __restrict__ aux, void* out,
    int N, int K, int nbn) {
  __shared__ __align__(16) short As[2][128 * 32];
  __shared__ __align__(16) short Bs[2][128 * 32];
  int nwg = gridDim.x;
  int qch = nwg >> 3;
  int flat = blockIdx.x;
  int wg = (flat & 7) * qch + (flat >> 3);
  int bm = wg / nbn, bn = wg % nbn;
  int tid = threadIdx.x;
  int w = tid >> 6, lane = tid & 63;
  int wr = w >> 1, wc = w & 1;
  int c0 = w * 64 + lane;
  int srow = c0 >> 2, skq = c0 & 3;
  const short* Aptr = (const short*)A;
  const short* Wbase = (const short*)(W + (size_t)(bn * 128) * K);
  f32x4 acc[4][4] = {};
  int lrow = lane & 15, kq = lane >> 4;

  auto arow = [&](int r) -> size_t {
    return AMAP ? ((size_t)r * 256 + bm) : ((size_t)(bm * 128 + r));
  };
  auto stage = [&](int buf, int k0) {
    load_lds16(Aptr + arow(srow) * K + k0 + skq * 8, &As[buf][c0 * 8]);
    load_lds16(Aptr + arow(srow + 64) * K + k0 + skq * 8,
               &As[buf][(256 + c0) * 8]);
    load_lds16(Wbase + (size_t)srow * K + k0 + skq * 8, &Bs[buf][c0 * 8]);
    load_lds16(Wbase + (size_t)(srow + 64) * K + k0 + skq * 8,
               &Bs[buf][(256 + c0) * 8]);
  };

  stage(0, 0);
  __syncthreads();
  int nk = K >> 5;
  for (int t = 0; t < nk; ++t) {
    int cur = t & 1;
    if (t + 1 < nk) stage(cur ^ 1, (t + 1) << 5);
    short8v af[4], bfv[4];
#pragma unroll
    for (int i = 0; i < 4; ++i)
      af[i] = *reinterpret_cast<const short8v*>(
          &As[cur][(wr * 64 + i * 16 + lrow) * 32 + kq * 8]);
#pragma unroll
    for (int j = 0; j < 4; ++j)
      bfv[j] = *reinterpret_cast<const short8v*>(
          &Bs[cur][(wc * 64 + j * 16 + lrow) * 32 + kq * 8]);
#pragma unroll
    for (int i = 0; i < 4; ++i)
#pragma unroll
      for (int j = 0; j < 4; ++j)
        acc[i][j] = __builtin_amdgcn_mfma_f32_16x16x32_bf16(bfv[j], af[i],
                                                            acc[i][j], 0, 0, 0);
    __syncthreads();
  }

  // epilogue: thread holds 4 consecutive output cols per (i,j)
  float* outF = (float*)out;
  bf16* outB = (bf16*)out;
  const float* auxF = (const float*)aux;
  const bf16* auxB = (const bf16*)aux;
#pragma unroll
  for (int j = 0; j < 4; ++j) {
    int cc = bn * 128 + wc * 64 + j * 16 + kq * 4;
    float4 bv4 = bias ? *reinterpret_cast<const float4*>(bias + cc)
                      : make_float4(0.f, 0.f, 0.f, 0.f);
#pragma unroll
    for (int i = 0; i < 4; ++i) {
      int lr = wr * 64 + i * 16 + lrow;
      size_t off = OMAP ? (((size_t)lr * 256 + bm) * N + cc)
                        : ((size_t)(bm * 128 + lr) * N + cc);
      float v0 = acc[i][j][0] + bv4.x;
      float v1 = acc[i][j][1] + bv4.y;
      float v2 = acc[i][j][2] + bv4.z;
      float v3 = acc[i][j][3] + bv4.w;
      if (EPI == 2) {
        float4 av = AUXB
                        ? bf4_to_f4(*reinterpret_cast<const ushort4*>(auxB + off))
                        : *reinterpret_cast<const float4*>(auxF + off);
        v0 += av.x; v1 += av.y; v2 += av.z; v3 += av.w;
      } else if (EPI == 3) {
        v0 = fmaxf(v0, 0.0f); v1 = fmaxf(v1, 0.0f);
        v2 = fmaxf(v2, 0.0f); v3 = fmaxf(v3, 0.0f);
      }
      if (OUTB || EPI == 0 || EPI == 3) {
        union { ushort4 u; bf16 h[4]; } cv;
        cv.h[0] = __float2bfloat16(v0);
        cv.h[1] = __float2bfloat16(v1);
        cv.h[2] = __float2bfloat16(v2);
        cv.h[3] = __float2bfloat16(v3);
        *reinterpret_cast<ushort4*>(outB + off) = cv.u;
      } else {
        *reinterpret_cast<float4*>(outF + off) = make_float4(v0, v1, v2, v3);
      }
    }
  }
}

// ---------------------------------------------------------------------------
// MFMA flash attention + fused gating, P-in-register, 512 threads (8 waves).
// Software-pipelined; L2E pre-folded (q-weights & bias) -> exp2 direct.
// ---------------------------------------------------------------------------
template <bool ROWMODE>
__global__ __launch_bounds__(512) void attn_mfma_kernel(
    const bf16* __restrict__ qkv, const float* __restrict__ bT,
    bf16* __restrict__ o) {
  constexpr int KVLEN = ROWMODE ? 256 : 128;
  constexpr int QT = ROWMODE ? 2 : 1;
  constexpr int KOUT = KVLEN / 64;
  constexpr int STRIDE = 1024;
  constexpr int NT = 512;
  __shared__ __align__(16) short K_lds[KVLEN * 32];
  __shared__ __align__(16) short Vt_lds[32 * KVLEN];

  int b = blockIdx.x;
  int idx = b >> 3, h = b & 7;
  const short* qb = (const short*)qkv + (size_t)idx * (KVLEN * 1024);
  const bf16* qbh = (const bf16*)qb;
  bf16* ob = o + (size_t)idx * (KVLEN * 256);
  int tid = threadIdx.x;
  int w = tid >> 6, lane = tid & 63;
  int l15 = lane & 15, l4 = lane >> 4;

#pragma unroll
  for (int rnd = 0; rnd < (KVLEN * 4) / NT; ++rnd) {
    int c = rnd * NT + tid;
    int row = c >> 2;
    int kq = (c & 3) ^ ((row >> 1) & 3);
    load_lds16(qb + (size_t)row * STRIDE + 256 + h * 32 + kq * 8,
               &K_lds[c * 8]);
  }
  {
    int tt = tid;
    if (KVLEN * 2 == NT || tt < KVLEN * 2) {
      int kp = tt >> 2;
      int cc = (tt & 3) * 8;
      short8v va = *reinterpret_cast<const short8v*>(
          qb + (size_t)(2 * kp) * STRIDE + 512 + h * 32 + cc);
      short8v vb = *reinterpret_cast<const short8v*>(
          qb + (size_t)(2 * kp + 1) * STRIDE + 512 + h * 32 + cc);
      int k = 2 * kp;
      int u = k >> 3;
      int klo = k & 7;
#pragma unroll
      for (int e = 0; e < 8; ++e) {
        int cI = cc + e;
        int up = u ^ (cI & 7);
        unsigned pk = (unsigned)(unsigned short)va[e] |
                      ((unsigned)(unsigned short)vb[e] << 16);
        *reinterpret_cast<unsigned*>(&Vt_lds[cI * KVLEN + up * 8 + klo]) = pk;
      }
    }
  }
  __syncthreads();

  int q0 = w * QT * 16;
  short8v qf[QT];
#pragma unroll
  for (int j = 0; j < QT; ++j)
    qf[j] = *reinterpret_cast<const short8v*>(
        qb + (size_t)(q0 + j * 16 + l15) * STRIDE + h * 32 + l4 * 8);

  f32x4 acc_o[QT][2] = {};
  f32x4 acc_l[QT] = {};
  const short4v ones = {0x3F80, 0x3F80, 0x3F80, 0x3F80};  // bf16 1.0
  const f32x4 zf = {0.f, 0.f, 0.f, 0.f};

  f32x4 accs[4];
  short4v P[4];
  float4 bb[4];

#define LOAD_BIAS(KT, JJ)                                                   \
  if (ROWMODE) {                                                            \
    const float* bq_ = bT + (size_t)h * 65536 +                             \
                       (size_t)(q0 + (JJ) * 16 + l15) * 256 + (KT) * 64 +   \
                       l4 * 4;                                              \
    _Pragma("unroll") for (int i_ = 0; i_ < 4; ++i_) bb[i_] =               \
        *reinterpret_cast<const float4*>(bq_ + i_ * 16);                    \
  }

#define DO_QK(KT, JJ)                                                       \
  {                                                                         \
    _Pragma("unroll") for (int i_ = 0; i_ < 4; ++i_) {                      \
      int krow_ = (KT) * 64 + i_ * 16 + l15;                                \
      short8v kf_ = *reinterpret_cast<const short8v*>(                      \
          &K_lds[krow_ * 32 + ((l4 ^ ((krow_ >> 1) & 3)) * 8)]);            \
      f32x4 cin_ = zf;                                                      \
      if (ROWMODE) {                                                        \
        cin_[0] = bb[i_].x; cin_[1] = bb[i_].y;                             \
        cin_[2] = bb[i_].z; cin_[3] = bb[i_].w;                             \
      }                                                                     \
      accs[i_] = __builtin_amdgcn_mfma_f32_16x16x32_bf16(kf_, qf[JJ], cin_, \
                                                         0, 0, 0);          \
    }                                                                       \
  }

#define DO_EXPPACK()                                                        \
  {                                                                         \
    _Pragma("unroll") for (int i_ = 0; i_ < 4; ++i_) {                      \
      float t0_ = exp2f(accs[i_][0]);                                       \
      float t1_ = exp2f(accs[i_][1]);                                       \
      float t2_ = exp2f(accs[i_][2]);                                       \
      float t3_ = exp2f(accs[i_][3]);                                       \
      union { unsigned u2[2]; short4v s; } pb_;                             \
      pb_.u2[0] = pack_bf16x2(t0_, t1_);                                    \
      pb_.u2[1] = pack_bf16x2(t2_, t3_);                                    \
      P[i_] = pb_.s;                                                        \
    }                                                                       \
  }

#define DO_PV(KT, JJ)                                                       \
  {                                                                         \
    _Pragma("unroll") for (int ks_ = 0; ks_ < 4; ++ks_) {                   \
      _Pragma("unroll") for (int ct_ = 0; ct_ < 2; ++ct_) {                 \
        int cI_ = ct_ * 16 + l15;                                           \
        int u_ = (KT) * 8 + ks_ * 2 + (l4 >> 1);                            \
        short4v vf_ = *reinterpret_cast<const short4v*>(                    \
            &Vt_lds[cI_ * KVLEN + (u_ ^ (cI_ & 7)) * 8 + (l4 & 1) * 4]);    \
        acc_o[JJ][ct_] = mfma16bf(vf_, P[ks_], acc_o[JJ][ct_]);             \
      }                                                                     \
      acc_l[JJ] = mfma16bf(ones, P[ks_], acc_l[JJ]);                        \
    }                                                                       \
  }

  if constexpr (QT == 2) {
    LOAD_BIAS(0, 0);
    DO_QK(0, 0);
    LOAD_BIAS(0, 1);
    DO_EXPPACK();  // pending = (0,0)
#pragma unroll 1
    for (int kt = 0; kt < KOUT; ++kt) {
      DO_QK(kt, 1);
      if (kt + 1 < KOUT) LOAD_BIAS(kt + 1, 0);
      DO_PV(kt, 0);
      DO_EXPPACK();  // pending = (kt,1)
      if (kt + 1 < KOUT) {
        DO_QK(kt + 1, 0);
        LOAD_BIAS(kt + 1, 1);
        DO_PV(kt, 1);
        DO_EXPPACK();  // pending = (kt+1,0)
      }
    }
    DO_PV(KOUT - 1, 1);
  } else {
    DO_QK(0, 0);
    DO_EXPPACK();
#pragma unroll 1
    for (int kt = 1; kt < KOUT; ++kt) {
      DO_QK(kt, 0);
      DO_PV(kt - 1, 0);
      DO_EXPPACK();
    }
    DO_PV(KOUT - 1, 0);
  }
#undef LOAD_BIAS
#undef DO_QK
#undef DO_EXPPACK
#undef DO_PV

#pragma unroll
  for (int j = 0; j < QT; ++j) {
    float inv = 1.0f / acc_l[j][0];
    int row = q0 + j * 16 + l15;
    const bf16* grow = qbh + (size_t)row * STRIDE + 768 + h * 32;
    bf16* orow = ob + (size_t)row * 256 + h * 32;
#pragma unroll
    for (int ct = 0; ct < 2; ++ct) {
      int cc = ct * 16 + l4 * 4;
      ushort4 gv = *reinterpret_cast<const ushort4*>(grow + cc);
      union { ushort4 u; bf16 h4[4]; } gu, ou;
      gu.u = gv;
#pragma unroll
      for (int r = 0; r < 4; ++r) {
        float gt = __bfloat162float(gu.h4[r]);
        float sg = 1.0f / (1.0f + __expf(-gt));
        ou.h4[r] = __float2bfloat16(acc_o[j][ct][r] * inv * sg);
      }
      *reinterpret_cast<ushort4*>(orow + cc) = ou.u;
    }
  }
}

// ---------------------------------------------------------------------------
extern "C" void kernel_launch(void* const* d_in, const int* in_sizes, int n_in,
                              void* d_out, int out_size, void* d_ws,
                              size_t ws_size, hipStream_t stream) {
  (void)in_sizes; (void)n_in; (void)out_size; (void)ws_size;
  const float* node      = (const float*)d_in[0];
  const float* pair      = (const float*)d_in[1];
  const float* ln_mr_g   = (const float*)d_in[2];
  const float* ln_mr_b   = (const float*)d_in[3];
  const float* ln_z_g    = (const float*)d_in[4];
  const float* ln_z_b    = (const float*)d_in[5];
  const float* b_weights = (const float*)d_in[6];
  const float* row_qkv_w = (const float*)d_in[7];
  const float* row_qkv_b = (const float*)d_in[8];
  const float* row_gate_w= (const float*)d_in[9];
  const float* row_gate_b= (const float*)d_in[10];
  const float* row_o_w   = (const float*)d_in[11];
  const float* out_bias  = (const float*)d_in[12];
  const float* ln_mc_g   = (const float*)d_in[13];
  const float* ln_mc_b   = (const float*)d_in[14];
  const float* col_qkv_w = (const float*)d_in[15];
  const float* col_qkv_b = (const float*)d_in[16];
  const float* col_gate_w= (const float*)d_in[17];
  const float* col_gate_b= (const float*)d_in[18];
  const float* col_o_w   = (const float*)d_in[19];
  const float* col_o_b   = (const float*)d_in[20];
  const float* ln_t_g    = (const float*)d_in[21];
  const float* ln_t_b    = (const float*)d_in[22];
  const float* t_w1      = (const float*)d_in[23];
  const float* t_b1      = (const float*)d_in[24];
  const float* t_w2      = (const float*)d_in[25];
  const float* t_b2      = (const float*)d_in[26];
  float* out = (float*)d_out;

  const size_t NR = 32768;
  char* p = (char*)d_ws;
  bf16* nodeB     = (bf16*)p;  p += NR * 256 * 2;   // bf16 residual stream
  char*  qkv_region = p;       p += NR * 1024 * 2;  // qkvg bf16 / h_bf
  float* buf_bias = (float*)p; p += 8 * 256 * 256 * 4;
  bf16* ln_bf     = (bf16*)p;  p += NR * 256 * 2;
  bf16* g_bf      = (bf16*)p;  p += NR * 256 * 2;
  bf16* qkv_bf = (bf16*)qkv_region;   // [32768][1024]: q|k|v|gate
  bf16* h_bf   = (bf16*)qkv_region;   // phase C: [32768][1024]
  bf16* w_rqkvg = (bf16*)p; p += 1024 * 256 * 2;
  bf16* w_ro    = (bf16*)p; p += 256 * 256 * 2;
  bf16* w_cqkvg = (bf16*)p; p += 1024 * 256 * 2;
  bf16* w_co    = (bf16*)p; p += 256 * 256 * 2;
  bf16* w_t1    = (bf16*)p; p += 1024 * 256 * 2;
  bf16* w_t2    = (bf16*)p; p += 256 * 1024 * 2;
  float* b_rqkvg = (float*)p; p += 1024 * 4;
  float* b_cqkvg = (float*)p; p += 1024 * 4;

  // ---- weight conversions in ONE launch; q-rows pre-scaled by s*log2(e) ----
  CvtArgs ca;
  ca.src[0] = row_qkv_w;  ca.dst[0] = w_rqkvg;             ca.n4[0] = 49152;
  ca.src[1] = row_gate_w; ca.dst[1] = w_rqkvg + 768 * 256; ca.n4[1] = 16384;
  ca.src[2] = row_o_w;    ca.dst[2] = w_ro;                ca.n4[2] = 16384;
  ca.src[3] = col_qkv_w;  ca.dst[3] = w_cqkvg;             ca.n4[3] = 49152;
  ca.src[4] = col_gate_w; ca.dst[4] = w_cqkvg + 768 * 256; ca.n4[4] = 16384;
  ca.src[5] = col_o_w;    ca.dst[5] = w_co;                ca.n4[5] = 16384;
  ca.src[6] = t_w1;       ca.dst[6] = w_t1;                ca.n4[6] = 65536;
  ca.src[7] = t_w2;       ca.dst[7] = w_t2;                ca.n4[7] = 65536;
  for (int s = 0; s < 8; ++s) ca.scale_n4[s] = 0;
  ca.scale_n4[0] = 16384;
  ca.scale_n4[3] = 16384;
  cvt_all_kernel<<<1152, 256, 0, stream>>>(ca);
  bias_concat_kernel<<<8, 256, 0, stream>>>(row_qkv_b, row_gate_b, col_qkv_b,
                                            col_gate_b, b_rqkvg, b_cqkvg);

  // ---- Phase A: MSARowAttentionWithPairBias ----
  ln256_bf_kernel<0><<<2048, 512, 0, stream>>>(node, ln_bf, ln_mr_g, ln_mr_b);
  pair_bias_kernel<<<1024, 256, 0, stream>>>(pair, ln_z_g, ln_z_b, b_weights,
                                             buf_bias);
  gemm_mfma_kernel<0, 0, 0, 0, 0><<<2048, 256, 0, stream>>>(
      ln_bf, w_rqkvg, b_rqkvg, nullptr, qkv_bf, 1024, 256, 8);
  attn_mfma_kernel<true><<<1024, 512, 0, stream>>>(qkv_bf, buf_bias, g_bf);
  // out = node(fp32) + o-proj + out_bias -> nodeB (bf16)
  gemm_mfma_kernel<2, 0, 0, 0, 1><<<512, 256, 0, stream>>>(
      g_bf, w_ro, out_bias, node, nodeB, 256, 256, 2);

  // ---- Phase B: MSAColumnAttention (transposed (r,s) layout end-to-end) ----
  ln256_bf_kernel<1><<<2048, 512, 0, stream>>>(nodeB, ln_bf, ln_mc_g, ln_mc_b);
  gemm_mfma_kernel<0, 1, 0, 0, 0><<<2048, 256, 0, stream>>>(
      ln_bf, w_cqkvg, b_cqkvg, nullptr, qkv_bf, 1024, 256, 8);
  attn_mfma_kernel<false><<<2048, 512, 0, stream>>>(qkv_bf, nullptr, g_bf);
  // in-place: nodeB += o-proj (bf16 aux, bf16 out; same offset per thread)
  gemm_mfma_kernel<2, 0, 1, 1, 1><<<512, 256, 0, stream>>>(
      g_bf, w_co, col_o_b, nodeB, nodeB, 256, 256, 2);

  // ---- Phase C: MSATransition ----
  ln256_bf_kernel<1><<<2048, 512, 0, stream>>>(nodeB, ln_bf, ln_t_g, ln_t_b);
  gemm_mfma_kernel<3, 0, 0, 0, 0><<<2048, 256, 0, stream>>>(
      ln_bf, w_t1, t_b1, nullptr, h_bf, 1024, 256, 8);
  // out(fp32) = nodeB(bf16) + t2 + b2
  gemm_mfma_kernel<2, 0, 0, 1, 0><<<512, 256, 0, stream>>>(
      h_bf, w_t2, t_b2, nodeB, out, 256, 1024, 2);
}